// Round 15
// baseline (348.255 us; speedup 1.0000x reference)
//
#include <hip/hip_runtime.h>

typedef __attribute__((ext_vector_type(4)))  float   floatx4;
typedef __attribute__((ext_vector_type(16))) float   floatx16;
typedef __attribute__((ext_vector_type(8)))  __bf16  bf16x8;
typedef unsigned short ushort_t;
typedef __attribute__((ext_vector_type(8)))  ushort_t ushortx8;

typedef const unsigned int __attribute__((address_space(1)))* gptr_t;
typedef unsigned int __attribute__((address_space(3)))* lptr_t;

#define NIMG 32
#define H    112
#define W    112
#define CIN  128
#define COUT 256
#define HP   114
#define WP   114
#define HW   12544      // H*W; 12544 % 256 == 0 so every 256-row tile stays in one image

#define BM 256
#define BN 128
#define NT 18           // K = 3*3*128 = 1152 = 18*64
#define NBLK 3136       // 1568 M-tiles * 2 N-tiles; %8==0

#define PREPAD_BLOCKS 12996   // 32*114*114*8 / 256  (32B per thread)
#define WTRANS_BLOCKS 1152    // 3*3*256*128 / 256

// ---------- fp32 -> bf16 (round-to-nearest-even) ----------
__device__ __forceinline__ ushort_t f32_to_bf16(float f) {
    unsigned u = __float_as_uint(f);
    unsigned r = 0x7fffu + ((u >> 16) & 1u);
    return (ushort_t)((u + r) >> 16);
}

// ---------- Fused prepass (r8-verified, unchanged) ----------
__global__ __launch_bounds__(256) void prepass_fused(const float* __restrict__ in,
                                                     const float* __restrict__ k,
                                                     ushort_t* __restrict__ pad,
                                                     ushort_t* __restrict__ wt) {
    int bid = blockIdx.x;
    if (bid < PREPAD_BLOCKS) {
        int u    = bid * 256 + threadIdx.x;
        int ic16 = u & 7;
        int sp   = u >> 3;
        int iw   = sp % WP;
        int sp2  = sp / WP;
        int ih   = sp2 % HP;
        int n    = sp2 / HP;
        ushortx8 v0, v1;
        if (ih >= 1 && ih <= H && iw >= 1 && iw <= W) {
            const float* src = in + ((size_t)((n * H + (ih - 1)) * W + (iw - 1))) * CIN + ic16 * 16;
            floatx4 a = *reinterpret_cast<const floatx4*>(src);
            floatx4 b = *reinterpret_cast<const floatx4*>(src + 4);
            floatx4 c = *reinterpret_cast<const floatx4*>(src + 8);
            floatx4 d = *reinterpret_cast<const floatx4*>(src + 12);
#pragma unroll
            for (int j = 0; j < 4; ++j) {
                v0[j] = f32_to_bf16(a[j]); v0[4 + j] = f32_to_bf16(b[j]);
                v1[j] = f32_to_bf16(c[j]); v1[4 + j] = f32_to_bf16(d[j]);
            }
        } else {
#pragma unroll
            for (int j = 0; j < 8; ++j) { v0[j] = 0; v1[j] = 0; }
        }
        ushortx8* dst = reinterpret_cast<ushortx8*>(pad) + ((size_t)sp * 16 + ic16 * 2);
        dst[0] = v0;
        dst[1] = v1;
    } else {
        int t    = (bid - PREPAD_BLOCKS) * 256 + threadIdx.x;
        int ic   = t & 127;
        int oc   = (t >> 7) & 255;
        int khkw = t >> 15;
        wt[t] = f32_to_bf16(k[((size_t)(khkw * CIN + ic)) * COUT + oc]);
    }
}

// ---------- K-tile global offsets ----------
__device__ __forceinline__ int aoffK(int t) {
    int tap = t >> 1;
    return ((tap / 3) * WP + (tap % 3)) * CIN + (t & 1) * 64;
}
__device__ __forceinline__ int boffK(int t) {
    int tap = t >> 1;
    return tap * (COUT * CIN) + (t & 1) * 64;
}

// ---------- Main: 256x128 tile, 4 waves (2Mx2N of 128x64), 2 blocks/CU ----------
// Regime analysis (r13/r14 counters): r14 was LDS-read-BW-bound (64x64/wave =
// 32.8K FLOP per b128 read; 3blk x 16 reads x 8cyc = 1536 cyc/tile = wall);
// r13 was 1-block serialization-bound (244 unified regs). This structure fixes
// both: per-wave 128x64 (acc[4][2] = 128 AGPR, 43.7K FLOP/read), 4-wave block
// => VGPR+128 <= 256 keeps 8 waves/CU = 2 blocks; LDS 80KB = 2 blocks exactly.
// Per-SIMD MFMA demand 2x1024 = 2048 cyc/tile > LDS 1536 -> MFMA-bound regime.
// Per tile, 2 phases:
//  q0: read af(rblk0,1: 8) + bfr0(4); stage A'(0..3); MFMA cb0 (8); read bfr1
//      mid-cluster (4); MFMA cb1 (8); barrier. [no wait]
//  q1: read af(rblk2,3: 8); stage A'(4..7) + B'(0..3) (B single-buf: all B
//      reads are in q0, retired at the q0-end barrier); MFMA rblk2,3 (16);
//      vmcnt(0) [forces a'(8)+b'(4); a'0-3 ~2 phases slack, rest ~1; b' L2];
//      barrier.
// g-swizzle (r12-verified, conflict-free for 32x32 reads) on both sides.

__global__ __launch_bounds__(256, 2) void conv_mfma4(const ushort_t* __restrict__ pad,
                                                     const ushort_t* __restrict__ wt,
                                                     const float* __restrict__ bias,
                                                     float* __restrict__ out) {
    __shared__ __align__(16) ushort_t lds[40960];   // 80 KiB: A dbuf 2x16384, B @32768

    const int tid  = threadIdx.x;
    const int wid  = tid >> 6;
    const int lane = tid & 63;
    const int wm   = wid >> 1;       // 0..1 : 128-row band
    const int wn   = wid & 1;        // 0..1 : 64-col band
    const int bid  = blockIdx.x;
    const int swz  = (bid & 7) * (NBLK / 8) + (bid >> 3);   // XCD swizzle, bijective
    const int mi   = swz >> 1;       // 0..1567
    const int ni   = swz & 1;        // 0..1

    // ---- staging geometry: slice = 32 rows x 64 k = 4KB = 256 thr x 16B ----
    const int trow = tid >> 3;                                      // 0..31
    const int lc   = (tid & 7) ^ (trow & 7) ^ ((trow >> 3) & 3);    // g(trow)

    int offA[8];                     // 32-bit element offsets (pad < 2^31 elems)
#pragma unroll
    for (int s = 0; s < 8; ++s) {
        int m  = mi * BM + s * 32 + trow;
        int n  = m / HW;
        int r  = m % HW;
        int oh = r / W;
        int ow = r % W;
        offA[s] = ((n * HP + oh) * WP + ow) * CIN + lc * 8;
    }
    int offB[4];
#pragma unroll
    for (int s = 0; s < 4; ++s)
        offB[s] = (ni * BN + s * 32 + trow) * CIN + lc * 8;

    const int dstSlot = wid * 512;   // ushort offset within a 2048-ushort slice

#define STAGE_A(par, s_, oA)                                                                        \
    __builtin_amdgcn_global_load_lds((gptr_t)(pad + offA[s_] + (oA)),                               \
                                     (lptr_t)&lds[(par) * 16384 + (s_) * 2048 + dstSlot], 16, 0, 0);
#define STAGE_B(s_, oB)                                                                             \
    __builtin_amdgcn_global_load_lds((gptr_t)(wt + offB[s_] + (oB)),                                \
                                     (lptr_t)&lds[32768 + (s_) * 2048 + dstSlot], 16, 0, 0);

    // ---- read-side constants (32x32 fragments; g-swizzled) ----
    const int aBase = (wm * 4) * 2048 + (lane & 31) * 64;        // + par*16384 + rblk*2048
    const int bBase = 32768 + (wn * 2) * 2048 + (lane & 31) * 64; // + cb*2048
    const int gr    = (lane & 7) ^ ((lane >> 3) & 3);            // g(lane&31)
    int cOff[4];
#pragma unroll
    for (int ksl = 0; ksl < 4; ++ksl)
        cOff[ksl] = ((ksl * 2 + (lane >> 5)) ^ gr) * 8;

    floatx16 acc[4][2];
#pragma unroll
    for (int i = 0; i < 4; ++i)
#pragma unroll
        for (int j = 0; j < 2; ++j) acc[i][j] = (floatx16)0.0f;

    // ---- prologue: A(0) slices 0-7 + B(0) slices 0-3; full drain (once) ----
    {
        const int oA0 = aoffK(0);
        const int oB0 = boffK(0);
#pragma unroll
        for (int s = 0; s < 8; ++s) STAGE_A(0, s, oA0);
#pragma unroll
        for (int s = 0; s < 4; ++s) STAGE_B(s, oB0);
    }
    asm volatile("s_waitcnt vmcnt(0)" ::: "memory");
    __builtin_amdgcn_s_barrier();

    // ---- main loop ----
    for (int t = 0; t < NT; ++t) {
        const int par  = t & 1;
        const int parn = par ^ 1;
        const int oAn  = aoffK(t + 1);   // guarded
        const int oBn  = boffK(t + 1);   // guarded
        const int aB   = par * 16384 + aBase;
        bf16x8 af0[4], af1[4], b0[4], b1[4];

        // ======== phase 0 : rowblocks 0,1 ========
#pragma unroll
        for (int ksl = 0; ksl < 4; ++ksl) {
            af0[ksl] = *reinterpret_cast<const bf16x8*>(&lds[aB +        cOff[ksl]]);
            af1[ksl] = *reinterpret_cast<const bf16x8*>(&lds[aB + 2048 + cOff[ksl]]);
            b0[ksl]  = *reinterpret_cast<const bf16x8*>(&lds[bBase +     cOff[ksl]]);
        }
        if (t + 1 < NT) { STAGE_A(parn, 0, oAn); STAGE_A(parn, 1, oAn); STAGE_A(parn, 2, oAn); STAGE_A(parn, 3, oAn); }
        __builtin_amdgcn_s_setprio(1);
#pragma unroll
        for (int ksl = 0; ksl < 4; ++ksl) {
            acc[0][0] = __builtin_amdgcn_mfma_f32_32x32x16_bf16(af0[ksl], b0[ksl], acc[0][0], 0, 0, 0);
            acc[1][0] = __builtin_amdgcn_mfma_f32_32x32x16_bf16(af1[ksl], b0[ksl], acc[1][0], 0, 0, 0);
        }
#pragma unroll
        for (int ksl = 0; ksl < 4; ++ksl)   // bfr cb=1 mid-cluster (burst smoothing)
            b1[ksl] = *reinterpret_cast<const bf16x8*>(&lds[bBase + 2048 + cOff[ksl]]);
#pragma unroll
        for (int ksl = 0; ksl < 4; ++ksl) {
            acc[0][1] = __builtin_amdgcn_mfma_f32_32x32x16_bf16(af0[ksl], b1[ksl], acc[0][1], 0, 0, 0);
            acc[1][1] = __builtin_amdgcn_mfma_f32_32x32x16_bf16(af1[ksl], b1[ksl], acc[1][1], 0, 0, 0);
        }
        __builtin_amdgcn_s_setprio(0);
        __builtin_amdgcn_s_barrier();

        // ======== phase 1 : rowblocks 2,3 ========
#pragma unroll
        for (int ksl = 0; ksl < 4; ++ksl) {
            af0[ksl] = *reinterpret_cast<const bf16x8*>(&lds[aB + 4096 + cOff[ksl]]);
            af1[ksl] = *reinterpret_cast<const bf16x8*>(&lds[aB + 6144 + cOff[ksl]]);
        }
        if (t + 1 < NT) {
            STAGE_A(parn, 4, oAn); STAGE_A(parn, 5, oAn); STAGE_A(parn, 6, oAn); STAGE_A(parn, 7, oAn);
            STAGE_B(0, oBn); STAGE_B(1, oBn); STAGE_B(2, oBn); STAGE_B(3, oBn);
        }
        __builtin_amdgcn_s_setprio(1);
#pragma unroll
        for (int ksl = 0; ksl < 4; ++ksl) {
            acc[2][0] = __builtin_amdgcn_mfma_f32_32x32x16_bf16(af0[ksl], b0[ksl], acc[2][0], 0, 0, 0);
            acc[3][0] = __builtin_amdgcn_mfma_f32_32x32x16_bf16(af1[ksl], b0[ksl], acc[3][0], 0, 0, 0);
            acc[2][1] = __builtin_amdgcn_mfma_f32_32x32x16_bf16(af0[ksl], b1[ksl], acc[2][1], 0, 0, 0);
            acc[3][1] = __builtin_amdgcn_mfma_f32_32x32x16_bf16(af1[ksl], b1[ksl], acc[3][1], 0, 0, 0);
        }
        __builtin_amdgcn_s_setprio(0);
        if (t + 1 < NT) { asm volatile("s_waitcnt vmcnt(0)" ::: "memory"); }
        __builtin_amdgcn_s_barrier();
    }

    // ---- epilogue: 32x32 C/D map col=lane&31, row=(reg&3)+8*(reg>>2)+4*(lane>>5) ----
    const int colB = ni * BN + wn * 64 + (lane & 31);
    const int rowB = mi * BM + wm * 128 + 4 * (lane >> 5);
    float bv[2];
#pragma unroll
    for (int cb = 0; cb < 2; ++cb) bv[cb] = bias[colB + cb * 32];
#pragma unroll
    for (int rblk = 0; rblk < 4; ++rblk)
#pragma unroll
        for (int cb = 0; cb < 2; ++cb)
#pragma unroll
            for (int reg = 0; reg < 16; ++reg) {
                int row = rowB + rblk * 32 + (reg & 3) + 8 * (reg >> 2);
                out[(size_t)row * COUT + colB + cb * 32] = acc[rblk][cb][reg] + bv[cb];
            }
#undef STAGE_A
#undef STAGE_B
}

extern "C" void kernel_launch(void* const* d_in, const int* in_sizes, int n_in,
                              void* d_out, int out_size, void* d_ws, size_t ws_size,
                              hipStream_t stream) {
    const float* input = (const float*)d_in[0];
    const float* kern  = (const float*)d_in[1];
    const float* bias  = (const float*)d_in[2];
    float* out         = (float*)d_out;

    ushort_t* pad = (ushort_t*)d_ws;                          // 106,463,232 B
    ushort_t* wt  = pad + (size_t)NIMG * HP * WP * CIN;       // + 589,824 B

    prepass_fused<<<PREPAD_BLOCKS + WTRANS_BLOCKS, 256, 0, stream>>>(input, kern, pad, wt);
    conv_mfma4<<<NBLK, 256, 0, stream>>>(pad, wt, bias, out); // 3136 = 1568 M x 2 N
}

// Round 18
// 344.956 us; speedup vs baseline: 1.0096x; 1.0096x over previous
//
#include <hip/hip_runtime.h>

typedef __attribute__((ext_vector_type(4)))  float   floatx4;
typedef __attribute__((ext_vector_type(16))) float   floatx16;
typedef __attribute__((ext_vector_type(8)))  __bf16  bf16x8;
typedef unsigned short ushort_t;
typedef __attribute__((ext_vector_type(8)))  ushort_t ushortx8;

typedef const unsigned int __attribute__((address_space(1)))* gptr_t;
typedef unsigned int __attribute__((address_space(3)))* lptr_t;

#define NIMG 32
#define H    112
#define W    112
#define CIN  128
#define COUT 256
#define HP   114
#define WP   114
#define HW   12544      // H*W; 12544 % 256 == 0 so every 256-row tile stays in one image

#define BM 256
#define BN 128
#define NT 18           // K = 3*3*128 = 1152 = 18*64
#define NBLK 3136       // 1568 M-tiles * 2 N-tiles; %8==0

#define PREPAD_BLOCKS 12996   // 32*114*114*8 / 256  (32B per thread)
#define WTRANS_BLOCKS 1152    // 3*3*256*128 / 256

// ---------- fp32 -> bf16 (round-to-nearest-even) ----------
__device__ __forceinline__ ushort_t f32_to_bf16(float f) {
    unsigned u = __float_as_uint(f);
    unsigned r = 0x7fffu + ((u >> 16) & 1u);
    return (ushort_t)((u + r) >> 16);
}

// ---------- Fused prepass (r8-verified, unchanged) ----------
__global__ __launch_bounds__(256) void prepass_fused(const float* __restrict__ in,
                                                     const float* __restrict__ k,
                                                     ushort_t* __restrict__ pad,
                                                     ushort_t* __restrict__ wt) {
    int bid = blockIdx.x;
    if (bid < PREPAD_BLOCKS) {
        int u    = bid * 256 + threadIdx.x;
        int ic16 = u & 7;
        int sp   = u >> 3;
        int iw   = sp % WP;
        int sp2  = sp / WP;
        int ih   = sp2 % HP;
        int n    = sp2 / HP;
        ushortx8 v0, v1;
        if (ih >= 1 && ih <= H && iw >= 1 && iw <= W) {
            const float* src = in + ((size_t)((n * H + (ih - 1)) * W + (iw - 1))) * CIN + ic16 * 16;
            floatx4 a = *reinterpret_cast<const floatx4*>(src);
            floatx4 b = *reinterpret_cast<const floatx4*>(src + 4);
            floatx4 c = *reinterpret_cast<const floatx4*>(src + 8);
            floatx4 d = *reinterpret_cast<const floatx4*>(src + 12);
#pragma unroll
            for (int j = 0; j < 4; ++j) {
                v0[j] = f32_to_bf16(a[j]); v0[4 + j] = f32_to_bf16(b[j]);
                v1[j] = f32_to_bf16(c[j]); v1[4 + j] = f32_to_bf16(d[j]);
            }
        } else {
#pragma unroll
            for (int j = 0; j < 8; ++j) { v0[j] = 0; v1[j] = 0; }
        }
        ushortx8* dst = reinterpret_cast<ushortx8*>(pad) + ((size_t)sp * 16 + ic16 * 2);
        dst[0] = v0;
        dst[1] = v1;
    } else {
        int t    = (bid - PREPAD_BLOCKS) * 256 + threadIdx.x;
        int ic   = t & 127;
        int oc   = (t >> 7) & 255;
        int khkw = t >> 15;
        wt[t] = f32_to_bf16(k[((size_t)(khkw * CIN + ic)) * COUT + oc]);
    }
}

// ---------- K-tile global offsets ----------
__device__ __forceinline__ int aoffK(int t) {
    int tap = t >> 1;
    return ((tap / 3) * WP + (tap % 3)) * CIN + (t & 1) * 64;
}
__device__ __forceinline__ int boffK(int t) {
    int tap = t >> 1;
    return tap * (COUT * CIN) + (t & 1) * 64;
}

// ---------- Main: 256x128 tile, r15 layout, read-set-aligned slack waits ----------
// r17's NaN root cause: the block's q0 read-set is A slices {0,1,4,5} (per-wave
// 128-row bands: wm=0 reads slices 0,1; wm=1 reads 4,5), NOT {0,1,2,3} — r17's
// q1-end vmcnt(4) left slices {4,5,6,7} in flight and q0 (wm=1) read 4,5 raw.
// Fix: stage slice-sets matched to read-sets.
//   q0: stage S0' = A'(t+1){0,1,4,5};  q1: stage B' then S1' = A'(t+1){2,3,6,7}.
// Ledger (FIFO, uniform, audited):
//   q1-end(t-1): outstanding S0'(t)+B(t)+S1'(t)=12 -> vmcnt(4) drains S0'+B
//     (>=1-phase slack), leaves S1'(t).
//   t q0: reads S0(t) [drained] + B(t) [drained]; stages S0'(t+1);
//     q0-end vmcnt(4) drains S1(t) (1-phase slack >= HBM lat), leaves S0'(t+1).
//   t q1: reads S1(t) [just drained]; stages B'(4, L2-hot ~250cyc < MFMA wall)
//     + S1'(t+1); q1-end vmcnt(4) drains S0'(t+1)+B', leaves S1'(t+1).
// Edges: prologue full drain; t=0 q0-end no-op; t=NT-1: q0-end vmcnt(0)
// (q1 needs S1), q1-end no wait. B single-buffer race unchanged from r15
// (all B reads retire at q0-end barrier; B' staged at q1).

__global__ __launch_bounds__(256, 2) void conv_mfma4(const ushort_t* __restrict__ pad,
                                                     const ushort_t* __restrict__ wt,
                                                     const float* __restrict__ bias,
                                                     float* __restrict__ out) {
    __shared__ __align__(16) ushort_t lds[40960];   // 80 KiB: A dbuf 2x16384, B @32768

    const int tid  = threadIdx.x;
    const int wid  = tid >> 6;
    const int lane = tid & 63;
    const int wm   = wid >> 1;       // 0..1 : 128-row band
    const int wn   = wid & 1;        // 0..1 : 64-col band
    const int bid  = blockIdx.x;
    const int swz  = (bid & 7) * (NBLK / 8) + (bid >> 3);   // XCD swizzle, bijective
    const int mi   = swz >> 1;       // 0..1567
    const int ni   = swz & 1;        // 0..1

    // ---- staging geometry: slice = 32 rows x 64 k = 4KB = 256 thr x 16B ----
    const int trow = tid >> 3;                                      // 0..31
    const int lc   = (tid & 7) ^ (trow & 7) ^ ((trow >> 3) & 3);    // g(trow)

    int offA[8];
#pragma unroll
    for (int s = 0; s < 8; ++s) {
        int m  = mi * BM + s * 32 + trow;
        int n  = m / HW;
        int r  = m % HW;
        int oh = r / W;
        int ow = r % W;
        offA[s] = ((n * HP + oh) * WP + ow) * CIN + lc * 8;
    }
    int offB[4];
#pragma unroll
    for (int s = 0; s < 4; ++s)
        offB[s] = (ni * BN + s * 32 + trow) * CIN + lc * 8;

    const int dstSlot = wid * 512;   // ushort offset within a 2048-ushort slice

#define STAGE_A(par, s_, oA)                                                                        \
    __builtin_amdgcn_global_load_lds((gptr_t)(pad + offA[s_] + (oA)),                               \
                                     (lptr_t)&lds[(par) * 16384 + (s_) * 2048 + dstSlot], 16, 0, 0);
#define STAGE_B(s_, oB)                                                                             \
    __builtin_amdgcn_global_load_lds((gptr_t)(wt + offB[s_] + (oB)),                                \
                                     (lptr_t)&lds[32768 + (s_) * 2048 + dstSlot], 16, 0, 0);

    // ---- read-side constants (32x32 fragments; g-swizzled) ----
    const int aBase = (wm * 4) * 2048 + (lane & 31) * 64;          // + par*16384 + rblk*2048
    const int bBase = 32768 + (wn * 2) * 2048 + (lane & 31) * 64;  // + cb*2048
    const int gr    = (lane & 7) ^ ((lane >> 3) & 3);              // g(lane&31)
    int cOff[4];
#pragma unroll
    for (int ksl = 0; ksl < 4; ++ksl)
        cOff[ksl] = ((ksl * 2 + (lane >> 5)) ^ gr) * 8;

    floatx16 acc[4][2];
#pragma unroll
    for (int i = 0; i < 4; ++i)
#pragma unroll
        for (int j = 0; j < 2; ++j) acc[i][j] = (floatx16)0.0f;

    // ---- prologue: A(0) slices 0-7 + B(0) slices 0-3; full drain (once) ----
    {
        const int oA0 = aoffK(0);
        const int oB0 = boffK(0);
#pragma unroll
        for (int s = 0; s < 8; ++s) STAGE_A(0, s, oA0);
#pragma unroll
        for (int s = 0; s < 4; ++s) STAGE_B(s, oB0);
    }
    asm volatile("s_waitcnt vmcnt(0)" ::: "memory");
    __builtin_amdgcn_s_barrier();

    // ---- main loop ----
    for (int t = 0; t < NT; ++t) {
        const int par  = t & 1;
        const int parn = par ^ 1;
        const int oAn  = aoffK(t + 1);   // guarded
        const int oBn  = boffK(t + 1);   // guarded
        const int aB   = par * 16384 + aBase;
        bf16x8 af0[4], af1[4], b0[4], b1[4];

        // ======== phase 0 : rowblocks 0,1 (block-wide A read-set {0,1,4,5}) ========
#pragma unroll
        for (int ksl = 0; ksl < 4; ++ksl) {
            af0[ksl] = *reinterpret_cast<const bf16x8*>(&lds[aB +        cOff[ksl]]);
            af1[ksl] = *reinterpret_cast<const bf16x8*>(&lds[aB + 2048 + cOff[ksl]]);
            b0[ksl]  = *reinterpret_cast<const bf16x8*>(&lds[bBase +     cOff[ksl]]);
        }
        if (t + 1 < NT) { STAGE_A(parn, 0, oAn); STAGE_A(parn, 1, oAn); STAGE_A(parn, 4, oAn); STAGE_A(parn, 5, oAn); }
        __builtin_amdgcn_s_setprio(1);
#pragma unroll
        for (int ksl = 0; ksl < 4; ++ksl) {
            acc[0][0] = __builtin_amdgcn_mfma_f32_32x32x16_bf16(af0[ksl], b0[ksl], acc[0][0], 0, 0, 0);
            acc[1][0] = __builtin_amdgcn_mfma_f32_32x32x16_bf16(af1[ksl], b0[ksl], acc[1][0], 0, 0, 0);
        }
#pragma unroll
        for (int ksl = 0; ksl < 4; ++ksl)   // b1 reads mid-cluster (burst smoothing)
            b1[ksl] = *reinterpret_cast<const bf16x8*>(&lds[bBase + 2048 + cOff[ksl]]);
#pragma unroll
        for (int ksl = 0; ksl < 4; ++ksl) {
            acc[0][1] = __builtin_amdgcn_mfma_f32_32x32x16_bf16(af0[ksl], b1[ksl], acc[0][1], 0, 0, 0);
            acc[1][1] = __builtin_amdgcn_mfma_f32_32x32x16_bf16(af1[ksl], b1[ksl], acc[1][1], 0, 0, 0);
        }
        __builtin_amdgcn_s_setprio(0);
        // q0-end: drain S1(t) {2,3,6,7} (1 phase slack); leave S0'(t+1) in flight
        if (t < NT - 1) { asm volatile("s_waitcnt vmcnt(4)" ::: "memory"); }
        else            { asm volatile("s_waitcnt vmcnt(0)" ::: "memory"); }
        __builtin_amdgcn_s_barrier();

        // ======== phase 1 : rowblocks 2,3 (block-wide A read-set {2,3,6,7}) ========
#pragma unroll
        for (int ksl = 0; ksl < 4; ++ksl) {
            af0[ksl] = *reinterpret_cast<const bf16x8*>(&lds[aB + 4096 + cOff[ksl]]);
            af1[ksl] = *reinterpret_cast<const bf16x8*>(&lds[aB + 6144 + cOff[ksl]]);
        }
        if (t + 1 < NT) {
            STAGE_B(0, oBn); STAGE_B(1, oBn); STAGE_B(2, oBn); STAGE_B(3, oBn);   // B' first
            STAGE_A(parn, 2, oAn); STAGE_A(parn, 3, oAn); STAGE_A(parn, 6, oAn); STAGE_A(parn, 7, oAn);
        }
        __builtin_amdgcn_s_setprio(1);
#pragma unroll
        for (int ksl = 0; ksl < 4; ++ksl) {
            acc[2][0] = __builtin_amdgcn_mfma_f32_32x32x16_bf16(af0[ksl], b0[ksl], acc[2][0], 0, 0, 0);
            acc[3][0] = __builtin_amdgcn_mfma_f32_32x32x16_bf16(af1[ksl], b0[ksl], acc[3][0], 0, 0, 0);
            acc[2][1] = __builtin_amdgcn_mfma_f32_32x32x16_bf16(af0[ksl], b1[ksl], acc[2][1], 0, 0, 0);
            acc[3][1] = __builtin_amdgcn_mfma_f32_32x32x16_bf16(af1[ksl], b1[ksl], acc[3][1], 0, 0, 0);
        }
        __builtin_amdgcn_s_setprio(0);
        // q1-end: drain S0'(t+1) (1 phase) + B' (L2-hot, covered by MFMA wall);
        // leave S1'(t+1) {2,3,6,7} in flight (first read at t+1 q1)
        if (t < NT - 1) { asm volatile("s_waitcnt vmcnt(4)" ::: "memory"); }
        __builtin_amdgcn_s_barrier();
    }

    // ---- epilogue: 32x32 C/D map col=lane&31, row=(reg&3)+8*(reg>>2)+4*(lane>>5) ----
    const int colB = ni * BN + wn * 64 + (lane & 31);
    const int rowB = mi * BM + wm * 128 + 4 * (lane >> 5);
    float bv[2];
#pragma unroll
    for (int cb = 0; cb < 2; ++cb) bv[cb] = bias[colB + cb * 32];
#pragma unroll
    for (int rblk = 0; rblk < 4; ++rblk)
#pragma unroll
        for (int cb = 0; cb < 2; ++cb)
#pragma unroll
            for (int reg = 0; reg < 16; ++reg) {
                int row = rowB + rblk * 32 + (reg & 3) + 8 * (reg >> 2);
                out[(size_t)row * COUT + colB + cb * 32] = acc[rblk][cb][reg] + bv[cb];
            }
#undef STAGE_A
#undef STAGE_B
}

extern "C" void kernel_launch(void* const* d_in, const int* in_sizes, int n_in,
                              void* d_out, int out_size, void* d_ws, size_t ws_size,
                              hipStream_t stream) {
    const float* input = (const float*)d_in[0];
    const float* kern  = (const float*)d_in[1];
    const float* bias  = (const float*)d_in[2];
    float* out         = (float*)d_out;

    ushort_t* pad = (ushort_t*)d_ws;                          // 106,463,232 B
    ushort_t* wt  = pad + (size_t)NIMG * HP * WP * CIN;       // + 589,824 B

    prepass_fused<<<PREPAD_BLOCKS + WTRANS_BLOCKS, 256, 0, stream>>>(input, kern, pad, wt);
    conv_mfma4<<<NBLK, 256, 0, stream>>>(pad, wt, bias, out); // 3136 = 1568 M x 2 N
}